// Round 2
// baseline (347.744 us; speedup 1.0000x reference)
//
#include <hip/hip_runtime.h>
#include <math.h>

#define NN 1600      // H*W
#define BB 8         // batch
#define CC 64        // channels
#define KK 10        // top-k
#define ROWS (BB*NN) // 12800

__device__ __forceinline__ unsigned long long minu64(unsigned long long a, unsigned long long b) {
    return a < b ? a : b;
}

// ---------------------------------------------------------------------------
// Kernel 1: pre[b,n] = relu( sum_c x[b,c,n]*w_con1[c] + b_con1 )
// ---------------------------------------------------------------------------
__global__ void conv_relu_kernel(const float* __restrict__ x, const float* __restrict__ w,
                                 const float* __restrict__ bsc, float* __restrict__ pre) {
    int gid = blockIdx.x * 256 + threadIdx.x;
    if (gid >= ROWS) return;
    int b = gid / NN, n = gid % NN;
    const float* xb = x + (size_t)b * CC * NN;
    float acc = bsc[0];
#pragma unroll 16
    for (int c = 0; c < CC; ++c) acc = fmaf(xb[(size_t)c * NN + n], w[c], acc);
    pre[gid] = fmaxf(acc, 0.f);
}

// ---------------------------------------------------------------------------
// Kernel 2: xx[b,:] = softmax(pre[b,:]) over the 1600 spatial positions
// ---------------------------------------------------------------------------
__global__ void softmax_kernel(const float* __restrict__ pre, float* __restrict__ xx) {
    __shared__ float xs[NN];
    __shared__ float red[256];
    int b = blockIdx.x, tid = threadIdx.x;
    for (int n = tid; n < NN; n += 256) xs[n] = pre[b * NN + n];
    __syncthreads();
    float m = -1e30f;
    for (int n = tid; n < NN; n += 256) m = fmaxf(m, xs[n]);
    red[tid] = m; __syncthreads();
    for (int s = 128; s > 0; s >>= 1) { if (tid < s) red[tid] = fmaxf(red[tid], red[tid + s]); __syncthreads(); }
    float mx = red[0]; __syncthreads();
    float ls = 0.f;
    for (int n = tid; n < NN; n += 256) { float e = expf(xs[n] - mx); xs[n] = e; ls += e; }
    red[tid] = ls; __syncthreads();
    for (int s = 128; s > 0; s >>= 1) { if (tid < s) red[tid] += red[tid + s]; __syncthreads(); }
    float S = red[0];
    for (int n = tid; n < NN; n += 256) xx[b * NN + n] = xs[n] / S;
}

// ---------------------------------------------------------------------------
// Kernel 3: per row i, the 10 lexicographically-smallest (|xx_i-xx_j|, j)
// == first 10 of a stable ascending argsort (matches jnp.argsort ties).
// kill-the-winner + static tree-min: short dependency chains, issue-bound.
// One wave per row, 4 rows (same batch) per block.
// ---------------------------------------------------------------------------
__global__ void __launch_bounds__(256) topk_kernel(const float* __restrict__ xx,
                                                   int* __restrict__ topk, int* __restrict__ DV) {
    __shared__ float xs[NN];
    int tid = threadIdx.x;
    int wid = tid >> 6, lane = tid & 63;
    int row = blockIdx.x * 4 + wid;     // all 4 rows share one batch
    int b = row / NN, i = row % NN;
    for (int t = tid; t < NN; t += 256) xs[t] = xx[b * NN + t];
    __syncthreads();
    float xi = xs[i];
    unsigned long long key[25];
#pragma unroll
    for (int s = 0; s < 25; ++s) {
        int j = lane + 64 * s;
        float d = fabsf(xi - xs[j]);
        key[s] = ((unsigned long long)__float_as_uint(d) << 32) | (unsigned)j;
    }
    int win[KK];
    bool in_top = false;
#pragma unroll
    for (int r = 0; r < KK; ++r) {
        // static tree-min over the 25 live keys (killed keys = ~0ull)
        unsigned long long t13[13];
#pragma unroll
        for (int s = 0; s < 12; ++s) t13[s] = minu64(key[s], key[s + 13]);
        t13[12] = key[12];
        unsigned long long t7[7];
#pragma unroll
        for (int s = 0; s < 6; ++s) t7[s] = minu64(t13[s], t13[s + 7]);
        t7[6] = t13[6];
        unsigned long long t4[4];
#pragma unroll
        for (int s = 0; s < 3; ++s) t4[s] = minu64(t7[s], t7[s + 4]);
        t4[3] = t7[3];
        unsigned long long best = minu64(minu64(t4[0], t4[2]), minu64(t4[1], t4[3]));
        // cross-lane butterfly min
#pragma unroll
        for (int off = 32; off > 0; off >>= 1) {
            unsigned long long o = __shfl_xor(best, off, 64);
            best = minu64(best, o);
        }
        int j = (int)(best & 0xffffffffu);
        win[r] = j;
        in_top = in_top || (j == i);
        // kill the winner (exactly one slot on one lane matches)
#pragma unroll
        for (int s = 0; s < 25; ++s) key[s] = (key[s] == best) ? ~0ull : key[s];
    }
    if (lane == 0) {
#pragma unroll
        for (int r = 0; r < KK - 1; ++r) {
            topk[row * KK + r] = win[r];
            atomicAdd(&DV[b * NN + win[r]], 1);
        }
        int fin = in_top ? win[KK - 1] : i;
        topk[row * KK + KK - 1] = fin;
        atomicAdd(&DV[b * NN + fin], 1);
    }
}

// ---------------------------------------------------------------------------
// Kernel 4: dv2 = DV^(-1/2)
// ---------------------------------------------------------------------------
__global__ void dv2_kernel(const int* __restrict__ DV, float* __restrict__ dv2) {
    int i = blockIdx.x * 256 + threadIdx.x;
    if (i < ROWS) dv2[i] = 1.0f / sqrtf((float)DV[i]);
}

// ---------------------------------------------------------------------------
// Kernel 5: P[row,c] = 0.1 * dv2[row] * ( in_row @ W + bias )[c]
// transform=1: in_row[c] := relu(dv2[row] * in[row,c])
// One wave per row (lane = output channel). Broadcast via v_readlane
// (constant lane index -> VALU, not LDS pipe).
// ---------------------------------------------------------------------------
__global__ void __launch_bounds__(256) lin_kernel(const float* __restrict__ in,
                                                  const float* __restrict__ W,
                                                  const float* __restrict__ bias,
                                                  const float* __restrict__ dv2,
                                                  float* __restrict__ outP, int transform) {
    __shared__ float Wl[CC * CC];
    __shared__ float bl[CC];
    int tid = threadIdx.x;
    for (int t = tid; t < CC * CC; t += 256) Wl[t] = W[t];
    if (tid < CC) bl[tid] = bias[tid];
    __syncthreads();
    int lane = tid & 63, wid = tid >> 6;
    int gw = blockIdx.x * 4 + wid;
    int nw = gridDim.x * 4;
    for (int row = gw; row < ROWS; row += nw) {
        float d = dv2[row];
        float vin = in[(size_t)row * CC + lane];
        if (transform) vin = fmaxf(d * vin, 0.f);
        int vbits = __float_as_int(vin);
        float acc = bl[lane];
#pragma unroll
        for (int kk = 0; kk < CC; ++kk) {
            float xv = __int_as_float(__builtin_amdgcn_readlane(vbits, kk));
            acc = fmaf(xv, Wl[kk * CC + lane], acc);
        }
        outP[(size_t)row * CC + lane] = 0.1f * d * acc;
    }
}

// ---------------------------------------------------------------------------
// Kernel 6: fused hyperedge gather + scatter.
// z[e,c] = sum_t P[v_t, c];  Acc[v_t, c] += z[e,c]  for all 10 members.
// ---------------------------------------------------------------------------
__global__ void __launch_bounds__(256) edge_kernel(const float* __restrict__ P,
                                                   const int* __restrict__ topk,
                                                   float* __restrict__ Acc) {
    int wid = threadIdx.x >> 6, lane = threadIdx.x & 63;
    int e = blockIdx.x * 4 + wid;
    if (e >= ROWS) return;
    int b = e / NN;
    const int* tk = topk + e * KK;
    int v[KK];
#pragma unroll
    for (int t = 0; t < KK; ++t) v[t] = tk[t];
    float z = 0.f;
#pragma unroll
    for (int t = 0; t < KK; ++t) z += P[((size_t)b * NN + v[t]) * CC + lane];
#pragma unroll
    for (int t = 0; t < KK; ++t) atomicAdd(&Acc[((size_t)b * NN + v[t]) * CC + lane], z);
}

// ---------------------------------------------------------------------------
// Kernel 7: final conv + relu + per-batch sum.
// ---------------------------------------------------------------------------
__global__ void final_kernel(const float* __restrict__ Acc, const float* __restrict__ dv2,
                             const float* __restrict__ w, const float* __restrict__ bsc,
                             float* __restrict__ out) {
    __shared__ float red[256];
    int blk = blockIdx.x;           // 0..63
    int b = blk >> 3, chunk = blk & 7;
    int tid = threadIdx.x;
    float local = 0.f;
    if (tid < 200) {
        int n = chunk * 200 + tid;
        int q = n >> 6, r = n & 63;
        float acc = bsc[0];
#pragma unroll 8
        for (int c = 0; c < CC; ++c) {
            int rowl = c * 25 + q;
            float v = Acc[((size_t)b * NN + rowl) * CC + r];
            float h = fmaxf(dv2[b * NN + rowl] * v, 0.f);
            acc = fmaf(h, w[c], acc);
        }
        local = fmaxf(acc, 0.f);
    }
    red[tid] = local; __syncthreads();
    for (int s = 128; s > 0; s >>= 1) { if (tid < s) red[tid] += red[tid + s]; __syncthreads(); }
    if (tid == 0) atomicAdd(&out[b], red[0]);
}

// ---------------------------------------------------------------------------
extern "C" void kernel_launch(void* const* d_in, const int* in_sizes, int n_in,
                              void* d_out, int out_size, void* d_ws, size_t ws_size,
                              hipStream_t stream) {
    const float* x      = (const float*)d_in[0];
    const float* w_con1 = (const float*)d_in[1];
    const float* b_con1 = (const float*)d_in[2];
    const float* W1     = (const float*)d_in[3];
    const float* b1     = (const float*)d_in[4];
    const float* W2     = (const float*)d_in[5];
    const float* b2     = (const float*)d_in[6];
    const float* w_con2 = (const float*)d_in[7];
    const float* b_con2 = (const float*)d_in[8];

    char* ws = (char*)d_ws;
    float* xx   = (float*)(ws + 0);        //  51200 B
    float* dv2  = (float*)(ws + 51200);    //  51200 B
    int*   DV   = (int*)  (ws + 102400);   //  51200 B
    float* pre  = (float*)(ws + 153600);   //  51200 B
    int*   topk = (int*)  (ws + 204800);   // 512000 B
    float* P    = (float*)(ws + 716800);   // 3276800 B
    float* Acc  = (float*)(ws + 3993600);  // 3276800 B

    float* out = (float*)d_out;

    conv_relu_kernel<<<(ROWS + 255) / 256, 256, 0, stream>>>(x, w_con1, b_con1, pre);
    softmax_kernel<<<BB, 256, 0, stream>>>(pre, xx);

    hipMemsetAsync(DV, 0, ROWS * sizeof(int), stream);
    topk_kernel<<<ROWS / 4, 256, 0, stream>>>(xx, topk, DV);
    dv2_kernel<<<(ROWS + 255) / 256, 256, 0, stream>>>(DV, dv2);

    lin_kernel<<<400, 256, 0, stream>>>(x, W1, b1, dv2, P, 0);
    hipMemsetAsync(Acc, 0, (size_t)ROWS * CC * sizeof(float), stream);
    edge_kernel<<<ROWS / 4, 256, 0, stream>>>(P, topk, Acc);

    lin_kernel<<<400, 256, 0, stream>>>(Acc, W2, b2, dv2, P, 1);
    hipMemsetAsync(Acc, 0, (size_t)ROWS * CC * sizeof(float), stream);
    edge_kernel<<<ROWS / 4, 256, 0, stream>>>(P, topk, Acc);

    hipMemsetAsync(out, 0, BB * sizeof(float), stream);
    final_kernel<<<64, 256, 0, stream>>>(Acc, dv2, w_con2, b_con2, out);
}

// Round 3
// 250.524 us; speedup vs baseline: 1.3881x; 1.3881x over previous
//
#include <hip/hip_runtime.h>
#include <math.h>

#define NN 1600      // H*W
#define BB 8         // batch
#define CC 64        // channels
#define KK 10        // top-k
#define ROWS (BB*NN) // 12800
#define SORTN 2048

// ---------------------------------------------------------------------------
// Kernel 1: pre[b,n] = relu( sum_c x[b,c,n]*w_con1[c] + b_con1 )
// ---------------------------------------------------------------------------
__global__ void conv_relu_kernel(const float* __restrict__ x, const float* __restrict__ w,
                                 const float* __restrict__ bsc, float* __restrict__ pre) {
    int gid = blockIdx.x * 256 + threadIdx.x;
    if (gid >= ROWS) return;
    int b = gid / NN, n = gid % NN;
    const float* xb = x + (size_t)b * CC * NN;
    float acc = bsc[0];
#pragma unroll 16
    for (int c = 0; c < CC; ++c) acc = fmaf(xb[(size_t)c * NN + n], w[c], acc);
    pre[gid] = fmaxf(acc, 0.f);
}

// ---------------------------------------------------------------------------
// Kernel 2: xx[b,:] = softmax(pre[b,:]) over the 1600 spatial positions
// ---------------------------------------------------------------------------
__global__ void softmax_kernel(const float* __restrict__ pre, float* __restrict__ xx) {
    __shared__ float xs[NN];
    __shared__ float red[256];
    int b = blockIdx.x, tid = threadIdx.x;
    for (int n = tid; n < NN; n += 256) xs[n] = pre[b * NN + n];
    __syncthreads();
    float m = -1e30f;
    for (int n = tid; n < NN; n += 256) m = fmaxf(m, xs[n]);
    red[tid] = m; __syncthreads();
    for (int s = 128; s > 0; s >>= 1) { if (tid < s) red[tid] = fmaxf(red[tid], red[tid + s]); __syncthreads(); }
    float mx = red[0]; __syncthreads();
    float ls = 0.f;
    for (int n = tid; n < NN; n += 256) { float e = expf(xs[n] - mx); xs[n] = e; ls += e; }
    red[tid] = ls; __syncthreads();
    for (int s = 128; s > 0; s >>= 1) { if (tid < s) red[tid] += red[tid + s]; __syncthreads(); }
    float S = red[0];
    for (int n = tid; n < NN; n += 256) xx[b * NN + n] = xs[n] / S;
}

// ---------------------------------------------------------------------------
// Kernel 3a: per batch, bitonic-sort the 1600 (value,index) pairs as u64 keys
// (float bits << 32 | j : positive floats -> bit order == value order, ties by j),
// then compute per-position group metadata:
//   gst[p] = start of maximal equal-value run containing p
//   gen[p] = end (exclusive) of that run
//   pos[j] = sorted position of original index j
// One block of 512 threads per batch.
// ---------------------------------------------------------------------------
__global__ void __launch_bounds__(512) sort_kernel(const float* __restrict__ xx,
                                                   float* __restrict__ sval, int* __restrict__ sidx,
                                                   int* __restrict__ gst, int* __restrict__ gen,
                                                   int* __restrict__ pos) {
    __shared__ unsigned long long sk[SORTN];
    __shared__ int ga[SORTN];
    __shared__ int gb[SORTN];
    int b = blockIdx.x, tid = threadIdx.x;
    for (int p = tid; p < SORTN; p += 512) {
        if (p < NN) {
            unsigned vb = __float_as_uint(xx[b * NN + p]);
            sk[p] = ((unsigned long long)vb << 32) | (unsigned)p;
        } else sk[p] = ~0ull;
    }
    __syncthreads();
    // bitonic sort (ascending)
    for (int k = 2; k <= SORTN; k <<= 1) {
        for (int j = k >> 1; j > 0; j >>= 1) {
            for (int i = tid; i < SORTN; i += 512) {
                int ixj = i ^ j;
                if (ixj > i) {
                    unsigned long long a = sk[i], c = sk[ixj];
                    bool up = ((i & k) == 0);
                    if ((a > c) == up) { sk[i] = c; sk[ixj] = a; }
                }
            }
            __syncthreads();
        }
    }
    // group boundary flags
    for (int p = tid; p < SORTN; p += 512) {
        if (p < NN) {
            unsigned v = (unsigned)(sk[p] >> 32);
            unsigned pv = (p > 0) ? (unsigned)(sk[p - 1] >> 32) : 0u;
            ga[p] = (p == 0 || v != pv) ? p : 0;
            unsigned nv = (p + 1 < NN) ? (unsigned)(sk[p + 1] >> 32) : 0u;
            gb[p] = (p + 1 >= NN || v != nv) ? (p + 1) : 0x7fffffff;
        } else { ga[p] = 0; gb[p] = 0x7fffffff; }
    }
    __syncthreads();
    // inclusive max-scan (ga, left->right) and min-scan (gb, right->left)
    for (int off = 1; off < SORTN; off <<= 1) {
        int va[4], vb2[4];
#pragma unroll
        for (int e = 0; e < 4; ++e) {
            int p = tid + e * 512;
            va[e]  = (p >= off) ? ga[p - off] : 0;
            vb2[e] = (p + off < SORTN) ? gb[p + off] : 0x7fffffff;
        }
        __syncthreads();
#pragma unroll
        for (int e = 0; e < 4; ++e) {
            int p = tid + e * 512;
            if (va[e] > ga[p]) ga[p] = va[e];
            if (vb2[e] < gb[p]) gb[p] = vb2[e];
        }
        __syncthreads();
    }
    for (int p = tid; p < NN; p += 512) {
        unsigned long long kkey = sk[p];
        int j = (int)(kkey & 0xffffffffu);
        sval[b * NN + p] = __uint_as_float((unsigned)(kkey >> 32));
        sidx[b * NN + p] = j;
        gst[b * NN + p] = ga[p];
        gen[b * NN + p] = gb[p];
        pos[b * NN + j] = p;
    }
}

// ---------------------------------------------------------------------------
// Kernel 3b: per row i, walk the sorted array to get the 10 lexicographically
// smallest (|xi-xj|, j) == first 10 of stable ascending argsort. d is computed
// with the same float subtraction as the reference (IEEE sub is exactly
// antisymmetric, so xi-v / v-xi == |xi-v| bitwise). Equal-d runs across
// value-groups are merged by ascending j (rescan-merge).
// Center-replacement (slot 9 := i when i not in top-10) can only trigger on
// the fast path (self group >= 10), since otherwise the whole self group
// (incl. i) is taken. DV accumulated via per-block LDS histogram.
// One block per 200 rows; 8 blocks per batch.
// ---------------------------------------------------------------------------
__global__ void __launch_bounds__(256) walk_kernel(const float* __restrict__ sval,
                                                   const int* __restrict__ sidx,
                                                   const int* __restrict__ gst,
                                                   const int* __restrict__ gen,
                                                   const int* __restrict__ pos,
                                                   int* __restrict__ topk, int* __restrict__ DV) {
    __shared__ float val[NN];
    __shared__ int   idx[NN];
    __shared__ int   gs[NN];
    __shared__ int   ge[NN];
    __shared__ int   hist[NN];
    int blk = blockIdx.x;
    int b = blk >> 3, chunk = blk & 7;
    int tid = threadIdx.x;
    for (int p = tid; p < NN; p += 256) {
        val[p] = sval[b * NN + p];
        idx[p] = sidx[b * NN + p];
        gs[p]  = gst[b * NN + p];
        ge[p]  = gen[b * NN + p];
        hist[p] = 0;
    }
    __syncthreads();
    int win[KK];
    bool active = tid < 200;
    int i = chunk * 200 + tid;
    if (active) {
        int p = pos[b * NN + i];
        float xi = val[p];
        int g0 = gs[p], g1 = ge[p];
        if (g1 - g0 >= KK) {
            // fast path: answer = first 10 j's of self group (all d == 0)
#pragma unroll
            for (int r = 0; r < KK; ++r) win[r] = idx[g0 + r];
            bool in_top = (p - g0) < KK;
            if (!in_top) win[KK - 1] = i;
        } else {
            int cnt = 0;
            for (int q = g0; q < g1; ++q) win[cnt++] = idx[q];   // self group, d=0
            int L = g0 - 1, R = g1;
            while (cnt < KK) {
                float dL = (L >= 0) ? xi - val[L] : __builtin_inff();
                float dR = (R < NN) ? val[R] - xi : __builtin_inff();
                float dm = fminf(dL, dR);
                int La = NN, Lb = -1, Ra = NN, Rb = -1;
                if (dL == dm) {
                    Lb = L; La = gs[L];
                    while (La - 1 >= 0 && (xi - val[La - 1]) == dm) La = gs[La - 1];
                }
                if (dR == dm) {
                    Ra = R; Rb = ge[R] - 1;
                    while (Rb + 1 < NN && (val[Rb + 1] - xi) == dm) Rb = ge[Rb + 1] - 1;
                }
                bool oneL = (Lb >= 0) && (Rb < 0) && (La == gs[Lb]);      // single left group
                bool oneR = (Rb >= 0) && (Lb < 0) && (Rb == ge[Ra] - 1);  // single right group
                if (oneL) {
                    for (int q = La; q <= Lb && cnt < KK; ++q) win[cnt++] = idx[q];
                } else if (oneR) {
                    for (int q = Ra; q <= Rb && cnt < KK; ++q) win[cnt++] = idx[q];
                } else {
                    // tie across groups/sides: take ascending j among all tied entries
                    int last = -1;
                    while (cnt < KK) {
                        int best = 0x7fffffff;
                        for (int q = La; q <= Lb; ++q) { int jj = idx[q]; if (jj > last && jj < best) best = jj; }
                        for (int q = Ra; q <= Rb; ++q) { int jj = idx[q]; if (jj > last && jj < best) best = jj; }
                        if (best == 0x7fffffff) break;
                        win[cnt++] = best; last = best;
                    }
                }
                if (Lb >= 0) L = La - 1;
                if (Rb >= 0) R = Rb + 1;
            }
            // in_top is necessarily true here (whole self group taken)
        }
#pragma unroll
        for (int r = 0; r < KK; ++r) {
            topk[(size_t)(b * NN + i) * KK + r] = win[r];
            atomicAdd(&hist[win[r]], 1);
        }
    }
    __syncthreads();
    for (int p = tid; p < NN; p += 256) {
        int h = hist[p];
        if (h) atomicAdd(&DV[b * NN + p], h);
    }
}

// ---------------------------------------------------------------------------
// Kernel 4: dv2 = DV^(-1/2)
// ---------------------------------------------------------------------------
__global__ void dv2_kernel(const int* __restrict__ DV, float* __restrict__ dv2) {
    int i = blockIdx.x * 256 + threadIdx.x;
    if (i < ROWS) dv2[i] = 1.0f / sqrtf((float)DV[i]);
}

// ---------------------------------------------------------------------------
// Kernel 5: P[row,c] = 0.1 * dv2[row] * ( in_row @ W + bias )[c]
// transform=1: in_row[c] := relu(dv2[row] * in[row,c])
// ---------------------------------------------------------------------------
__global__ void __launch_bounds__(256) lin_kernel(const float* __restrict__ in,
                                                  const float* __restrict__ W,
                                                  const float* __restrict__ bias,
                                                  const float* __restrict__ dv2,
                                                  float* __restrict__ outP, int transform) {
    __shared__ float Wl[CC * CC];
    __shared__ float bl[CC];
    int tid = threadIdx.x;
    for (int t = tid; t < CC * CC; t += 256) Wl[t] = W[t];
    if (tid < CC) bl[tid] = bias[tid];
    __syncthreads();
    int lane = tid & 63, wid = tid >> 6;
    int gw = blockIdx.x * 4 + wid;
    int nw = gridDim.x * 4;
    for (int row = gw; row < ROWS; row += nw) {
        float d = dv2[row];
        float vin = in[(size_t)row * CC + lane];
        if (transform) vin = fmaxf(d * vin, 0.f);
        int vbits = __float_as_int(vin);
        float acc = bl[lane];
#pragma unroll
        for (int kk = 0; kk < CC; ++kk) {
            float xv = __int_as_float(__builtin_amdgcn_readlane(vbits, kk));
            acc = fmaf(xv, Wl[kk * CC + lane], acc);
        }
        outP[(size_t)row * CC + lane] = 0.1f * d * acc;
    }
}

// ---------------------------------------------------------------------------
// Kernel 6: fused hyperedge gather + scatter.
// ---------------------------------------------------------------------------
__global__ void __launch_bounds__(256) edge_kernel(const float* __restrict__ P,
                                                   const int* __restrict__ topk,
                                                   float* __restrict__ Acc) {
    int wid = threadIdx.x >> 6, lane = threadIdx.x & 63;
    int e = blockIdx.x * 4 + wid;
    if (e >= ROWS) return;
    int b = e / NN;
    const int* tk = topk + e * KK;
    int v[KK];
#pragma unroll
    for (int t = 0; t < KK; ++t) v[t] = tk[t];
    float z = 0.f;
#pragma unroll
    for (int t = 0; t < KK; ++t) z += P[((size_t)b * NN + v[t]) * CC + lane];
#pragma unroll
    for (int t = 0; t < KK; ++t) atomicAdd(&Acc[((size_t)b * NN + v[t]) * CC + lane], z);
}

// ---------------------------------------------------------------------------
// Kernel 7: final conv + relu + per-batch sum.
// ---------------------------------------------------------------------------
__global__ void final_kernel(const float* __restrict__ Acc, const float* __restrict__ dv2,
                             const float* __restrict__ w, const float* __restrict__ bsc,
                             float* __restrict__ out) {
    __shared__ float red[256];
    int blk = blockIdx.x;
    int b = blk >> 3, chunk = blk & 7;
    int tid = threadIdx.x;
    float local = 0.f;
    if (tid < 200) {
        int n = chunk * 200 + tid;
        int q = n >> 6, r = n & 63;
        float acc = bsc[0];
#pragma unroll 8
        for (int c = 0; c < CC; ++c) {
            int rowl = c * 25 + q;
            float v = Acc[((size_t)b * NN + rowl) * CC + r];
            float h = fmaxf(dv2[b * NN + rowl] * v, 0.f);
            acc = fmaf(h, w[c], acc);
        }
        local = fmaxf(acc, 0.f);
    }
    red[tid] = local; __syncthreads();
    for (int s = 128; s > 0; s >>= 1) { if (tid < s) red[tid] += red[tid + s]; __syncthreads(); }
    if (tid == 0) atomicAdd(&out[b], red[0]);
}

// ---------------------------------------------------------------------------
extern "C" void kernel_launch(void* const* d_in, const int* in_sizes, int n_in,
                              void* d_out, int out_size, void* d_ws, size_t ws_size,
                              hipStream_t stream) {
    const float* x      = (const float*)d_in[0];
    const float* w_con1 = (const float*)d_in[1];
    const float* b_con1 = (const float*)d_in[2];
    const float* W1     = (const float*)d_in[3];
    const float* b1     = (const float*)d_in[4];
    const float* W2     = (const float*)d_in[5];
    const float* b2     = (const float*)d_in[6];
    const float* w_con2 = (const float*)d_in[7];
    const float* b_con2 = (const float*)d_in[8];

    char* ws = (char*)d_ws;
    float* xx   = (float*)(ws + 0);        //  51200 B
    float* dv2  = (float*)(ws + 51200);    //  51200 B
    int*   DV   = (int*)  (ws + 102400);   //  51200 B
    float* pre  = (float*)(ws + 153600);   //  51200 B
    int*   topk = (int*)  (ws + 204800);   // 512000 B
    float* P    = (float*)(ws + 716800);   // 3276800 B
    float* Acc  = (float*)(ws + 3993600);  // 3276800 B
    // sort scratch lives in P's region (dead until lin_kernel writes P):
    float* sval = (float*)(ws + 716800);
    int*   sidx = (int*)  (ws + 716800 + 51200);
    int*   gst  = (int*)  (ws + 716800 + 102400);
    int*   gen  = (int*)  (ws + 716800 + 153600);
    int*   pos  = (int*)  (ws + 716800 + 204800);

    float* out = (float*)d_out;

    conv_relu_kernel<<<(ROWS + 255) / 256, 256, 0, stream>>>(x, w_con1, b_con1, pre);
    softmax_kernel<<<BB, 256, 0, stream>>>(pre, xx);

    hipMemsetAsync(DV, 0, ROWS * sizeof(int), stream);
    sort_kernel<<<BB, 512, 0, stream>>>(xx, sval, sidx, gst, gen, pos);
    walk_kernel<<<64, 256, 0, stream>>>(sval, sidx, gst, gen, pos, topk, DV);
    dv2_kernel<<<(ROWS + 255) / 256, 256, 0, stream>>>(DV, dv2);

    lin_kernel<<<400, 256, 0, stream>>>(x, W1, b1, dv2, P, 0);
    hipMemsetAsync(Acc, 0, (size_t)ROWS * CC * sizeof(float), stream);
    edge_kernel<<<ROWS / 4, 256, 0, stream>>>(P, topk, Acc);

    lin_kernel<<<400, 256, 0, stream>>>(Acc, W2, b2, dv2, P, 1);
    hipMemsetAsync(Acc, 0, (size_t)ROWS * CC * sizeof(float), stream);
    edge_kernel<<<ROWS / 4, 256, 0, stream>>>(P, topk, Acc);

    hipMemsetAsync(out, 0, BB * sizeof(float), stream);
    final_kernel<<<64, 256, 0, stream>>>(Acc, dv2, w_con2, b_con2, out);
}